// Round 1
// baseline (12.009 us; speedup 1.0000x reference)
//
#include <hip/hip_runtime.h>
#include <math.h>

#define NPAIRS 7

__device__ __forceinline__ float2 cmul(float2 a, float2 b) {
    // a*b
    return make_float2(fmaf(a.x, b.x, -a.y * b.y), fmaf(a.x, b.y, a.y * b.x));
}
__device__ __forceinline__ float2 cmulc(float2 a, float2 b) {
    // a*conj(b)
    return make_float2(fmaf(a.x, b.x, a.y * b.y), fmaf(a.y, b.x, -a.x * b.y));
}
__device__ __forceinline__ float2 cadd(float2 a, float2 b) {
    return make_float2(a.x + b.x, a.y + b.y);
}

// 2x2 Hermitian density matrix: [[d0, o],[conj(o), d1]]
struct Herm { float d0, d1; float2 o; };

// rho' = Tr_b[ M (A (x) B) M^dagger ], keeping qubit "a" (the high bit of index 2a+b).
// Mk points at 16 float2 (row-major 4x4) in LDS.
__device__ __forceinline__ Herm chan(const Herm A, const Herm B, const float2* __restrict__ Mk) {
    float2 Mr[16];
#pragma unroll
    for (int i = 0; i < 16; ++i) Mr[i] = Mk[i];

    float2 Af[2][2], Bf[2][2];
    Af[0][0] = make_float2(A.d0, 0.f);       Af[0][1] = A.o;
    Af[1][0] = make_float2(A.o.x, -A.o.y);   Af[1][1] = make_float2(A.d1, 0.f);
    Bf[0][0] = make_float2(B.d0, 0.f);       Bf[0][1] = B.o;
    Bf[1][0] = make_float2(B.o.x, -B.o.y);   Bf[1][1] = make_float2(B.d1, 0.f);

    // rho[(2i+m)][(2k+l)] = A[i][k]*B[m][l]
    float2 rho[4][4];
#pragma unroll
    for (int i = 0; i < 2; ++i)
#pragma unroll
        for (int m = 0; m < 2; ++m)
#pragma unroll
            for (int k = 0; k < 2; ++k)
#pragma unroll
                for (int l = 0; l < 2; ++l)
                    rho[2 * i + m][2 * k + l] = cmul(Af[i][k], Bf[m][l]);

    // N = M * rho
    float2 N[4][4];
#pragma unroll
    for (int p = 0; p < 4; ++p)
#pragma unroll
        for (int s = 0; s < 4; ++s) {
            float2 acc = make_float2(0.f, 0.f);
#pragma unroll
            for (int r = 0; r < 4; ++r) acc = cadd(acc, cmul(Mr[4 * p + r], rho[r][s]));
            N[p][s] = acc;
        }

    // T[p][q] = sum_s N[p][s] * conj(M[q][s])
#define TPQ(p, q)                                                        \
    ({                                                                   \
        float2 acc_ = make_float2(0.f, 0.f);                             \
        _Pragma("unroll")                                                \
        for (int s_ = 0; s_ < 4; ++s_)                                   \
            acc_ = cadd(acc_, cmulc(N[p][s_], Mr[4 * (q) + s_]));        \
        acc_;                                                            \
    })

    float2 t00 = TPQ(0, 0);
    float2 t11 = TPQ(1, 1);
    float2 t22 = TPQ(2, 2);
    float2 t33 = TPQ(3, 3);
    float2 t02 = TPQ(0, 2);
    float2 t13 = TPQ(1, 3);
#undef TPQ

    Herm R;
    R.d0 = t00.x + t11.x;           // rho'_00 (real)
    R.d1 = t22.x + t33.x;           // rho'_11 (real)
    R.o  = cadd(t02, t13);          // rho'_01
    return R;
}

extern "C" __global__ void __launch_bounds__(256)
qcnn_kernel(const float* __restrict__ x, const float* __restrict__ w,
            float* __restrict__ out, int batch)
{
    __shared__ float2 M[NPAIRS][16];

    const int tid = threadIdx.x;
    if (tid < NPAIRS) {
        const int k = tid;
        const float w0 = w[2 * k];
        const float w1 = w[2 * k + 1];
        float zr, zi, c1, s1;
        // z = e^{i w0/2}
        sincosf(0.5f * w0, &zi, &zr);
        sincosf(0.5f * w1, &s1, &c1);
        const float cy = 0.92387953251128674f;  // cos(pi/8)
        const float sy = 0.38268343236508978f;  // sin(pi/8)

#pragma unroll
        for (int i = 0; i < 16; ++i) M[k][i] = make_float2(0.f, 0.f);

        // Composite M = CRY(pi/4; c=b,t=a) * CRX(w1; c=a,t=b) * CRZ(w0; c=a,t=b),
        // basis index = 2a+b.
        M[k][4 * 0 + 0] = make_float2(1.f, 0.f);
        M[k][4 * 1 + 1] = make_float2(cy, 0.f);
        M[k][4 * 1 + 2] = make_float2(sy * s1 * zi, sy * s1 * zr);     //  i*sy*s1*conj(z)
        M[k][4 * 1 + 3] = make_float2(-sy * c1 * zr, -sy * c1 * zi);   // -sy*c1*z
        M[k][4 * 2 + 2] = make_float2(c1 * zr, -c1 * zi);              //  c1*conj(z)
        M[k][4 * 2 + 3] = make_float2(s1 * zi, -s1 * zr);              // -i*s1*z
        M[k][4 * 3 + 1] = make_float2(sy, 0.f);
        M[k][4 * 3 + 2] = make_float2(-cy * s1 * zi, -cy * s1 * zr);   // -i*cy*s1*conj(z)
        M[k][4 * 3 + 3] = make_float2(cy * c1 * zr, cy * c1 * zi);     //  cy*c1*z
    }
    __syncthreads();

    const int idx = blockIdx.x * 256 + tid;
    if (idx >= batch) return;

    // load x[idx][0..7] as two float4 (32B, coalesced)
    const float4 xa = reinterpret_cast<const float4*>(x)[2 * idx];
    const float4 xb = reinterpret_cast<const float4*>(x)[2 * idx + 1];
    const float xv[8] = {xa.x, xa.y, xa.z, xa.w, xb.x, xb.y, xb.z, xb.w};

    // single-qubit density matrices
    Herm r[8];
#pragma unroll
    for (int q = 0; q < 8; ++q) {
        float s, c;
        sincosf(xv[q], &s, &c);
        r[q].d0 = 0.5f * (1.f + c);
        r[q].d1 = 0.5f * (1.f - c);
        r[q].o  = make_float2(0.f, 0.5f * s);   // i*sin(x)/2
    }

    // tree contraction
    const Herm r01 = chan(r[0], r[1], M[0]);
    const Herm r23 = chan(r[2], r[3], M[1]);
    const Herm r45 = chan(r[4], r[5], M[2]);
    const Herm r67 = chan(r[6], r[7], M[3]);
    const Herm rA  = chan(r01, r23, M[4]);
    const Herm rB  = chan(r45, r67, M[5]);
    const Herm rF  = chan(rA, rB, M[6]);

    out[idx] = rF.d0 - rF.d1;   // <Z_0>
}

extern "C" void kernel_launch(void* const* d_in, const int* in_sizes, int n_in,
                              void* d_out, int out_size, void* d_ws, size_t ws_size,
                              hipStream_t stream) {
    const float* x = (const float*)d_in[0];
    const float* w = (const float*)d_in[1];
    float* out = (float*)d_out;
    const int batch = in_sizes[0] / 8;
    const int block = 256;
    const int grid = (batch + block - 1) / block;
    qcnn_kernel<<<grid, block, 0, stream>>>(x, w, out, batch);
}